// Round 4
// baseline (418.321 us; speedup 1.0000x reference)
//
#include <hip/hip_runtime.h>
#include <hip/hip_bf16.h>

// GATv2Conv: N=100000, E=1000000, D_IN=128, D_OUT=64, D_EDGE=11
// heads=1, add_self_loops fill='mean', negative_slope=0.2
//
// R4: (a) attr reordered into CSR order at placement (bf16, 24 B records)
//     so k_fused's only random access is the 128 B xlb gather;
//     (b) xr stored bf16; (c) k_gemm B-fragments staged via LDS (fixes
//     the 256-scalar-load issue-bound inner loop of R3).

#define NN 100000
#define EE 1000000
#define DI 128
#define DO 64
#define DE 11
#define NEG 0.2f

typedef __attribute__((ext_vector_type(8))) short short8;
typedef __attribute__((ext_vector_type(4))) float f32x4;

// ---- workspace layout (bytes), total ~52.8 MB ----
#define XRB_B   ((size_t)0)            // NN*DO*2 = 12,800,000 (bf16 xr)
#define XLB_B   ((size_t)12800000)     // NN*DO*2 = 12,800,000 (bf16 xl)
#define SRC_B   ((size_t)25600000)     // EE*4    =  4,000,000 (src per slot)
#define APERM_B ((size_t)29600000)     // EE*24   = 24,000,000 (bf16 attr recs)
#define START_B ((size_t)53600000)     // NN*4
#define CUR_B   ((size_t)54000000)     // NN*4
#define DEG_B   ((size_t)54400000)     // NN*4
#define CNT_B   ((size_t)54800000)     // 4 (contiguous after deg for memset)

__device__ inline float4 bf4_to_f4(uint2 r) {
  float4 f;
  f.x = __uint_as_float(r.x << 16);
  f.y = __uint_as_float(r.x & 0xFFFF0000u);
  f.z = __uint_as_float(r.y << 16);
  f.w = __uint_as_float(r.y & 0xFFFF0000u);
  return f;
}

__device__ inline float bfu_to_f(unsigned short u) {
  return __uint_as_float(((unsigned)u) << 16);
}

__device__ inline short f2bfs(float v) {
  union { __hip_bfloat16 b; short s; } u;
  u.b = __float2bfloat16(v);
  return u.s;
}

// ---- GEMM: xl = x@Wl, xr = x@Wr, both bf16 out, MFMA with LDS-staged B ----
__global__ __launch_bounds__(256) void k_gemm(
    const float* __restrict__ x, const float* __restrict__ Wl,
    const float* __restrict__ Wr, unsigned short* __restrict__ xlb,
    unsigned short* __restrict__ xrb) {
  // B fragments pre-swizzled: [ks][nb][quad][l16][j] shorts (16 KB/matrix)
  __shared__ short wldsL[8192];
  __shared__ short wldsR[8192];
  for (int t = threadIdx.x; t < 8192; t += 256) {
    int k = t >> 6, n = t & 63;  // t = k*64 + n
    int off = ((((k >> 5) * 4 + (n >> 4)) * 4 + ((k >> 3) & 3)) * 16 + (n & 15)) * 8 + (k & 7);
    wldsL[off] = f2bfs(Wl[t]);
    wldsR[off] = f2bfs(Wr[t]);
  }
  __syncthreads();

  int wave = threadIdx.x >> 6;
  int lane = threadIdx.x & 63;
  int quad = lane >> 4;
  int l16 = lane & 15;
  int m0 = (blockIdx.x * 4 + wave) * 16;
  int row = m0 + l16;
  bool rowok = row < NN;

  f32x4 accL[4], accR[4];
#pragma unroll
  for (int nb = 0; nb < 4; ++nb) {
    accL[nb] = (f32x4){0.f, 0.f, 0.f, 0.f};
    accR[nb] = (f32x4){0.f, 0.f, 0.f, 0.f};
  }

#pragma unroll
  for (int ks = 0; ks < 4; ++ks) {
    short8 a;
    if (rowok) {
      const float* xp = x + (size_t)row * DI + ks * 32 + quad * 8;
      float4 v0 = *(const float4*)xp;
      float4 v1 = *(const float4*)(xp + 4);
      a[0] = f2bfs(v0.x); a[1] = f2bfs(v0.y); a[2] = f2bfs(v0.z); a[3] = f2bfs(v0.w);
      a[4] = f2bfs(v1.x); a[5] = f2bfs(v1.y); a[6] = f2bfs(v1.z); a[7] = f2bfs(v1.w);
    } else {
#pragma unroll
      for (int j = 0; j < 8; ++j) a[j] = 0;
    }
#pragma unroll
    for (int nb = 0; nb < 4; ++nb) {
      int off = (((ks * 4 + nb) * 4 + quad) * 16 + l16) * 8;
      short8 bl = *(const short8*)(wldsL + off);
      short8 br = *(const short8*)(wldsR + off);
      accL[nb] = __builtin_amdgcn_mfma_f32_16x16x32_bf16(a, bl, accL[nb], 0, 0, 0);
      accR[nb] = __builtin_amdgcn_mfma_f32_16x16x32_bf16(a, br, accR[nb], 0, 0, 0);
    }
  }
  // D layout: row = quad*4 + reg, col = l16 (m89-verified, same as R3 pass)
#pragma unroll
  for (int reg = 0; reg < 4; ++reg) {
    int r = m0 + quad * 4 + reg;
    if (r < NN) {
      size_t base = (size_t)r * DO + l16;
#pragma unroll
      for (int nb = 0; nb < 4; ++nb) {
        xlb[base + nb * 16] = (unsigned short)f2bfs(accL[nb][reg]);
        xrb[base + nb * 16] = (unsigned short)f2bfs(accR[nb][reg]);
      }
    }
  }
}

__global__ __launch_bounds__(256) void k_deg(const int* __restrict__ ei,
                                             unsigned* __restrict__ deg) {
  int e = blockIdx.x * 256 + threadIdx.x;
  if (e < EE) atomicAdd(&deg[ei[EE + e]], 1u);
}

__global__ __launch_bounds__(256) void k_scan(const unsigned* __restrict__ deg,
                                              unsigned* __restrict__ start,
                                              unsigned* __restrict__ cursor,
                                              unsigned* __restrict__ counter) {
  int i = blockIdx.x * 256 + threadIdx.x;
  int lane = threadIdx.x & 63;
  unsigned d = (i < NN) ? deg[i] : 0u;
  unsigned incl = d;
#pragma unroll
  for (int sh = 1; sh < 64; sh <<= 1) {
    unsigned v = __shfl_up(incl, sh, 64);
    if (lane >= sh) incl += v;
  }
  unsigned total = __shfl(incl, 63, 64);
  unsigned base = 0;
  if (lane == 63) base = atomicAdd(counter, total);
  base = __shfl(base, 63, 64);
  unsigned s = base + incl - d;
  if (i < NN) { start[i] = s; cursor[i] = s; }
}

// placement: srcs[pos] = src; aperm[pos] = bf16(attr[e][0..10]) (24 B rec)
__global__ __launch_bounds__(256) void k_place(const int* __restrict__ ei,
                                               const float* __restrict__ attr,
                                               unsigned* __restrict__ cursor,
                                               unsigned* __restrict__ srcs,
                                               unsigned short* __restrict__ aperm) {
  int e = blockIdx.x * 256 + threadIdx.x;
  if (e >= EE) return;
  unsigned src = (unsigned)ei[e];
  unsigned dst = (unsigned)ei[EE + e];
  const float* ar = attr + (size_t)e * DE;  // coalesced-ish stream
  unsigned short h[12];
#pragma unroll
  for (int j = 0; j < DE; ++j) h[j] = (unsigned short)f2bfs(ar[j]);
  h[11] = 0;
  unsigned pos = atomicAdd(&cursor[dst], 1u);
  srcs[pos] = src;
  uint2* rp = (uint2*)(aperm + (size_t)pos * 12);  // 8B-aligned (24B stride)
  uint2 w0, w1, w2;
  w0.x = (unsigned)h[0] | ((unsigned)h[1] << 16);
  w0.y = (unsigned)h[2] | ((unsigned)h[3] << 16);
  w1.x = (unsigned)h[4] | ((unsigned)h[5] << 16);
  w1.y = (unsigned)h[6] | ((unsigned)h[7] << 16);
  w2.x = (unsigned)h[8] | ((unsigned)h[9] << 16);
  w2.y = (unsigned)h[10];
  rp[0] = w0; rp[1] = w1; rp[2] = w2;
}

__device__ inline void consume_edge(uint2 raw, float atv,
                                    const float4* __restrict__ Wreg,
                                    float4 a4, float4 xri, float4& acc,
                                    float& denom, float& asum) {
  float4 vl = bf4_to_f4(raw);
  float4 ev = {0.f, 0.f, 0.f, 0.f};
#pragma unroll
  for (int j = 0; j < DE; ++j) {
    float a = __shfl(atv, j, 16);  // lane j holds attr[e][j]
    ev.x += a * Wreg[j].x; ev.y += a * Wreg[j].y;
    ev.z += a * Wreg[j].z; ev.w += a * Wreg[j].w;
  }
  float4 m;
  m.x = vl.x + xri.x + ev.x;
  m.y = vl.y + xri.y + ev.y;
  m.z = vl.z + xri.z + ev.z;
  m.w = vl.w + xri.w + ev.w;
  m.x = m.x >= 0.f ? m.x : NEG * m.x;
  m.y = m.y >= 0.f ? m.y : NEG * m.y;
  m.z = m.z >= 0.f ? m.z : NEG * m.z;
  m.w = m.w >= 0.f ? m.w : NEG * m.w;
  float s = m.x * a4.x + m.y * a4.y + m.z * a4.z + m.w * a4.w;
  s += __shfl_xor(s, 1);
  s += __shfl_xor(s, 2);
  s += __shfl_xor(s, 4);
  s += __shfl_xor(s, 8);
  float ex = __expf(s);  // no max-subtraction: |logit| <~ 8, fp32-safe
  acc.x += ex * vl.x; acc.y += ex * vl.y;
  acc.z += ex * vl.z; acc.w += ex * vl.w;
  denom += ex;
  asum += atv;  // lane g accumulates attr[:,g] (0 for g>=11)
}

__global__ __launch_bounds__(256) void k_fused(
    const unsigned short* __restrict__ xlb, const unsigned short* __restrict__ xrb,
    const unsigned short* __restrict__ aperm, const float* __restrict__ We,
    const float* __restrict__ att, const unsigned* __restrict__ start,
    const unsigned* __restrict__ deg, const unsigned* __restrict__ srcs,
    float* __restrict__ out) {
  int t = blockIdx.x * 256 + threadIdx.x;
  int i = t >> 4;  // 16 lanes per dst node, 4 dims per lane
  int g = t & 15;
  if (i >= NN) return;
  unsigned s0 = start[i];
  unsigned d = deg[i];
  int k0 = g * 4;

  float4 Wreg[DE];
#pragma unroll
  for (int j = 0; j < DE; ++j) Wreg[j] = *(const float4*)(We + j * DO + k0);
  const float4 a4 = *(const float4*)(att + k0);
  float4 xri = bf4_to_f4(*(const uint2*)(xrb + (size_t)i * DO + k0));

  float4 acc = {0.f, 0.f, 0.f, 0.f};
  float denom = 0.f;
  float asum = 0.f;

  for (unsigned c = 0; c < d; c += 16) {
    unsigned rem = d - c;
    if (rem > 16) rem = 16;
    // coalesced src load: one dword per lane
    unsigned sv = srcs[s0 + c + ((unsigned)g < rem ? (unsigned)g : rem - 1)];
    // (1) issue all 16 xlb gathers (the only latency-exposed misses)
#define LD(ii)                                                            \
    uint2 R##ii = {0u, 0u};                                               \
    if ((unsigned)ii < rem) {                                             \
      unsigned s_ = __shfl(sv, ii, 16);                                   \
      R##ii = *(const uint2*)(xlb + (size_t)s_ * DO + k0);                \
    }
    LD(0) LD(1) LD(2) LD(3) LD(4) LD(5) LD(6) LD(7)
    LD(8) LD(9) LD(10) LD(11) LD(12) LD(13) LD(14) LD(15)
#undef LD
    // (2) attr records: sequential bf16 stream in slot order (L1-hot)
#define LA(ii)                                                            \
    float A##ii = 0.f;                                                    \
    if ((unsigned)ii < rem && g < DE)                                     \
      A##ii = bfu_to_f(aperm[(size_t)(s0 + c + ii) * 12 + g]);
    LA(0) LA(1) LA(2) LA(3) LA(4) LA(5) LA(6) LA(7)
    LA(8) LA(9) LA(10) LA(11) LA(12) LA(13) LA(14) LA(15)
#undef LA
    // (3) consume
#define CS(ii)                                                            \
    if ((unsigned)ii < rem)                                               \
      consume_edge(R##ii, A##ii, Wreg, a4, xri, acc, denom, asum);
    CS(0) CS(1) CS(2) CS(3) CS(4) CS(5) CS(6) CS(7)
    CS(8) CS(9) CS(10) CS(11) CS(12) CS(13) CS(14) CS(15)
#undef CS
  }

  // self-loop: loop_attr = mean incoming attr; ev = loop_attr @ We
  float la = asum / fmaxf((float)d, 1.0f);  // lanes g<11 valid
  float4 ev = {0.f, 0.f, 0.f, 0.f};
#pragma unroll
  for (int j = 0; j < DE; ++j) {
    float aj = __shfl(la, j, 16);
    ev.x += aj * Wreg[j].x; ev.y += aj * Wreg[j].y;
    ev.z += aj * Wreg[j].z; ev.w += aj * Wreg[j].w;
  }
  float4 xli = bf4_to_f4(*(const uint2*)(xlb + (size_t)i * DO + k0));
  float4 m;
  m.x = xli.x + xri.x + ev.x;
  m.y = xli.y + xri.y + ev.y;
  m.z = xli.z + xri.z + ev.z;
  m.w = xli.w + xri.w + ev.w;
  m.x = m.x >= 0.f ? m.x : NEG * m.x;
  m.y = m.y >= 0.f ? m.y : NEG * m.y;
  m.z = m.z >= 0.f ? m.z : NEG * m.z;
  m.w = m.w >= 0.f ? m.w : NEG * m.w;
  float s = m.x * a4.x + m.y * a4.y + m.z * a4.z + m.w * a4.w;
  s += __shfl_xor(s, 1);
  s += __shfl_xor(s, 2);
  s += __shfl_xor(s, 4);
  s += __shfl_xor(s, 8);
  float exs = __expf(s);
  float inv = 1.0f / (denom + exs);
  float4 o;
  o.x = (acc.x + exs * xli.x) * inv;
  o.y = (acc.y + exs * xli.y) * inv;
  o.z = (acc.z + exs * xli.z) * inv;
  o.w = (acc.w + exs * xli.w) * inv;
  *(float4*)(out + (size_t)i * DO + k0) = o;
}

extern "C" void kernel_launch(void* const* d_in, const int* in_sizes, int n_in,
                              void* d_out, int out_size, void* d_ws, size_t ws_size,
                              hipStream_t stream) {
  const float* x    = (const float*)d_in[0];
  const int*   ei   = (const int*)d_in[1];
  const float* attr = (const float*)d_in[2];
  const float* Wl   = (const float*)d_in[3];
  const float* Wr   = (const float*)d_in[4];
  const float* We   = (const float*)d_in[5];
  const float* att  = (const float*)d_in[6];
  float* out = (float*)d_out;

  char* ws = (char*)d_ws;
  unsigned short* xrb     = (unsigned short*)(ws + XRB_B);
  unsigned short* xlb     = (unsigned short*)(ws + XLB_B);
  unsigned*       srcs    = (unsigned*)(ws + SRC_B);
  unsigned short* aperm   = (unsigned short*)(ws + APERM_B);
  unsigned*       start   = (unsigned*)(ws + START_B);
  unsigned*       cursor  = (unsigned*)(ws + CUR_B);
  unsigned*       deg     = (unsigned*)(ws + DEG_B);
  unsigned*       counter = (unsigned*)(ws + CNT_B);

  hipMemsetAsync(deg, 0, (size_t)(NN + 1) * sizeof(unsigned), stream);

  k_gemm<<<(NN + 63) / 64, 256, 0, stream>>>(x, Wl, Wr, xlb, xrb);
  k_deg<<<(EE + 255) / 256, 256, 0, stream>>>(ei, deg);
  k_scan<<<(NN + 255) / 256, 256, 0, stream>>>(deg, start, cursor, counter);
  k_place<<<(EE + 255) / 256, 256, 0, stream>>>(ei, attr, cursor, srcs, aperm);
  k_fused<<<(NN * 16) / 256, 256, 0, stream>>>(xlb, xrb, aperm, We, att,
                                               start, deg, srcs, out);
}

// Round 5
// 367.116 us; speedup vs baseline: 1.1395x; 1.1395x over previous
//
#include <hip/hip_runtime.h>
#include <hip/hip_bf16.h>

// GATv2Conv: N=100000, E=1000000, D_IN=128, D_OUT=64, D_EDGE=11
// heads=1, add_self_loops fill='mean', negative_slope=0.2
//
// R5 primary: evec = attr@We materialized bf16 in CSR order (k_evec, also
// does placement). Self-loop uses linearity: mean(attr)@We = mean(evec),
// so k_fused needs no attr/We at all: per edge = 1 gather + 1 stream load
// + short VALU + 4 shfl_xor. k_gemm and k_deg fused into one dispatch.
// Fallback (ws_size < 158.8 MB): R4 path (aperm records).

#define NN 100000
#define EE 1000000
#define DI 128
#define DO 64
#define DE 11
#define NEG 0.2f
#define NGB 1563  // gemm blocks in k_gemm_deg; deg blocks follow

typedef __attribute__((ext_vector_type(8))) short short8;
typedef __attribute__((ext_vector_type(4))) float f32x4;

// ---- workspace layouts (bytes) ----
// shared prefix (both paths):
#define XRB_B   ((size_t)0)            // NN*DO*2 bf16 xr
#define XLB_B   ((size_t)12800000)     // NN*DO*2 bf16 xl
#define SRC_B   ((size_t)25600000)     // EE*4 src per slot
// primary layout:
#define EV_B    ((size_t)29600000)     // EE*DO*2 = 128,000,000 bf16 evec (CSR)
#define P_START ((size_t)157600000)
#define P_CUR   ((size_t)158000000)
#define P_DEG   ((size_t)158400000)
#define P_CNT   ((size_t)158800000)
#define P_NEED  ((size_t)158800004)
// fallback (R4) layout:
#define APERM_B ((size_t)29600000)     // EE*24 bf16 attr records
#define F_START ((size_t)53600000)
#define F_CUR   ((size_t)54000000)
#define F_DEG   ((size_t)54400000)
#define F_CNT   ((size_t)54800000)

__device__ inline float4 bf4_to_f4(uint2 r) {
  float4 f;
  f.x = __uint_as_float(r.x << 16);
  f.y = __uint_as_float(r.x & 0xFFFF0000u);
  f.z = __uint_as_float(r.y << 16);
  f.w = __uint_as_float(r.y & 0xFFFF0000u);
  return f;
}

__device__ inline float bfu_to_f(unsigned short u) {
  return __uint_as_float(((unsigned)u) << 16);
}

__device__ inline short f2bfs(float v) {
  union { __hip_bfloat16 b; short s; } u;
  u.b = __float2bfloat16(v);
  return u.s;
}

// ---- fused GEMM (blocks [0,NGB)) + degree count (blocks [NGB,..)) ----
__global__ __launch_bounds__(256) void k_gemm_deg(
    const float* __restrict__ x, const float* __restrict__ Wl,
    const float* __restrict__ Wr, const int* __restrict__ ei,
    unsigned short* __restrict__ xlb, unsigned short* __restrict__ xrb,
    unsigned* __restrict__ deg) {
  __shared__ short wldsL[8192];
  __shared__ short wldsR[8192];
  if (blockIdx.x >= NGB) {  // degree-count blocks
    int e = (blockIdx.x - NGB) * 256 + threadIdx.x;
    if (e < EE) atomicAdd(&deg[ei[EE + e]], 1u);
    return;
  }
  // B fragments pre-swizzled: [ks][nb][quad][l16][j] shorts
  for (int t = threadIdx.x; t < 8192; t += 256) {
    int k = t >> 6, n = t & 63;
    int off = ((((k >> 5) * 4 + (n >> 4)) * 4 + ((k >> 3) & 3)) * 16 + (n & 15)) * 8 + (k & 7);
    wldsL[off] = f2bfs(Wl[t]);
    wldsR[off] = f2bfs(Wr[t]);
  }
  __syncthreads();

  int wave = threadIdx.x >> 6;
  int lane = threadIdx.x & 63;
  int quad = lane >> 4;
  int l16 = lane & 15;
  int m0 = (blockIdx.x * 4 + wave) * 16;
  int row = m0 + l16;
  bool rowok = row < NN;

  f32x4 accL[4], accR[4];
#pragma unroll
  for (int nb = 0; nb < 4; ++nb) {
    accL[nb] = (f32x4){0.f, 0.f, 0.f, 0.f};
    accR[nb] = (f32x4){0.f, 0.f, 0.f, 0.f};
  }
#pragma unroll
  for (int ks = 0; ks < 4; ++ks) {
    short8 a;
    if (rowok) {
      const float* xp = x + (size_t)row * DI + ks * 32 + quad * 8;
      float4 v0 = *(const float4*)xp;
      float4 v1 = *(const float4*)(xp + 4);
      a[0] = f2bfs(v0.x); a[1] = f2bfs(v0.y); a[2] = f2bfs(v0.z); a[3] = f2bfs(v0.w);
      a[4] = f2bfs(v1.x); a[5] = f2bfs(v1.y); a[6] = f2bfs(v1.z); a[7] = f2bfs(v1.w);
    } else {
#pragma unroll
      for (int j = 0; j < 8; ++j) a[j] = 0;
    }
#pragma unroll
    for (int nb = 0; nb < 4; ++nb) {
      int off = (((ks * 4 + nb) * 4 + quad) * 16 + l16) * 8;
      short8 bl = *(const short8*)(wldsL + off);
      short8 br = *(const short8*)(wldsR + off);
      accL[nb] = __builtin_amdgcn_mfma_f32_16x16x32_bf16(a, bl, accL[nb], 0, 0, 0);
      accR[nb] = __builtin_amdgcn_mfma_f32_16x16x32_bf16(a, br, accR[nb], 0, 0, 0);
    }
  }
  // D layout: row = quad*4 + reg, col = l16 (m89-verified)
#pragma unroll
  for (int reg = 0; reg < 4; ++reg) {
    int r = m0 + quad * 4 + reg;
    if (r < NN) {
      size_t base = (size_t)r * DO + l16;
#pragma unroll
      for (int nb = 0; nb < 4; ++nb) {
        xlb[base + nb * 16] = (unsigned short)f2bfs(accL[nb][reg]);
        xrb[base + nb * 16] = (unsigned short)f2bfs(accR[nb][reg]);
      }
    }
  }
}

__global__ __launch_bounds__(256) void k_scan(const unsigned* __restrict__ deg,
                                              unsigned* __restrict__ start,
                                              unsigned* __restrict__ cursor,
                                              unsigned* __restrict__ counter) {
  int i = blockIdx.x * 256 + threadIdx.x;
  int lane = threadIdx.x & 63;
  unsigned d = (i < NN) ? deg[i] : 0u;
  unsigned incl = d;
#pragma unroll
  for (int sh = 1; sh < 64; sh <<= 1) {
    unsigned v = __shfl_up(incl, sh, 64);
    if (lane >= sh) incl += v;
  }
  unsigned total = __shfl(incl, 63, 64);
  unsigned base = 0;
  if (lane == 63) base = atomicAdd(counter, total);
  base = __shfl(base, 63, 64);
  unsigned s = base + incl - d;
  if (i < NN) { start[i] = s; cursor[i] = s; }
}

// ---- primary: placement + evec = attr@We (bf16, CSR slot order) ----
__global__ __launch_bounds__(256) void k_evec(
    const int* __restrict__ ei, const float* __restrict__ attr,
    const float* __restrict__ We, unsigned* __restrict__ cursor,
    unsigned* __restrict__ srcs, unsigned short* __restrict__ evec) {
  int g = threadIdx.x & 15;
  int k0 = g * 4;
  int grp = (blockIdx.x * 256 + threadIdx.x) >> 4;
  int gstride = (gridDim.x * 256) >> 4;
  float4 W[DE];
#pragma unroll
  for (int j = 0; j < DE; ++j) W[j] = *(const float4*)(We + j * DO + k0);
  for (int e = grp; e < EE; e += gstride) {
    unsigned src = (unsigned)ei[e];
    unsigned dst = (unsigned)ei[EE + e];
    const float* ar = attr + (size_t)e * DE;  // same addr across 16 lanes (L1 bcast)
    float4 ev = {0.f, 0.f, 0.f, 0.f};
#pragma unroll
    for (int j = 0; j < DE; ++j) {
      float a = ar[j];
      ev.x += a * W[j].x; ev.y += a * W[j].y;
      ev.z += a * W[j].z; ev.w += a * W[j].w;
    }
    unsigned pos;
    if (g == 0) pos = atomicAdd(&cursor[dst], 1u);
    pos = __shfl(pos, 0, 16);
    if (g == 0) srcs[pos] = src;
    uint2 w;
    w.x = ((unsigned)(unsigned short)f2bfs(ev.x)) |
          (((unsigned)(unsigned short)f2bfs(ev.y)) << 16);
    w.y = ((unsigned)(unsigned short)f2bfs(ev.z)) |
          (((unsigned)(unsigned short)f2bfs(ev.w)) << 16);
    // 16 lanes write one full 128-B record (2 whole lines, no partial-line RMW)
    *(uint2*)(evec + (size_t)pos * DO + k0) = w;
  }
}

// ---- primary fused pass: no attr, no We — evec stream + xlb gather ----
__global__ __launch_bounds__(128) void k_fused(
    const unsigned short* __restrict__ xlb, const unsigned short* __restrict__ xrb,
    const unsigned short* __restrict__ evec, const float* __restrict__ att,
    const unsigned* __restrict__ start, const unsigned* __restrict__ deg,
    const unsigned* __restrict__ srcs, float* __restrict__ out) {
  int t = blockIdx.x * 128 + threadIdx.x;
  int i = t >> 4;  // 16 lanes per dst node, 4 dims per lane
  int g = t & 15;
  if (i >= NN) return;
  unsigned s0 = start[i];
  unsigned d = deg[i];
  int k0 = g * 4;

  const float4 a4 = *(const float4*)(att + k0);
  float4 xri = bf4_to_f4(*(const uint2*)(xrb + (size_t)i * DO + k0));
  float4 xli = bf4_to_f4(*(const uint2*)(xlb + (size_t)i * DO + k0));

  float4 acc = {0.f, 0.f, 0.f, 0.f};
  float4 evs = {0.f, 0.f, 0.f, 0.f};
  float den = 0.f;

  for (unsigned c = 0; c < d; c += 8) {
    unsigned rem = d - c;
    if (rem > 8) rem = 8;
    size_t sp = s0 + c;
    // (1) evec stream loads (sequential, independent of src)
#define LE(ii)                                                              \
    uint2 E##ii = {0u, 0u};                                                 \
    if ((unsigned)ii < rem) E##ii = *(const uint2*)(evec + (sp + ii) * (size_t)DO + k0);
    LE(0) LE(1) LE(2) LE(3) LE(4) LE(5) LE(6) LE(7)
#undef LE
    // (2) src indices (same addr across 16 lanes, L1-hot line)
#define LS(ii)                                                              \
    unsigned S##ii = 0u;                                                    \
    if ((unsigned)ii < rem) S##ii = srcs[sp + ii];
    LS(0) LS(1) LS(2) LS(3) LS(4) LS(5) LS(6) LS(7)
#undef LS
    // (3) xl gathers (the latency-exposed misses, 8 in flight)
#define LR(ii)                                                              \
    uint2 R##ii = {0u, 0u};                                                 \
    if ((unsigned)ii < rem) R##ii = *(const uint2*)(xlb + (size_t)S##ii * DO + k0);
    LR(0) LR(1) LR(2) LR(3) LR(4) LR(5) LR(6) LR(7)
#undef LR
    // (4) consume
#define CS(ii)                                                              \
    if ((unsigned)ii < rem) {                                               \
      float4 vl = bf4_to_f4(R##ii);                                         \
      float4 ev = bf4_to_f4(E##ii);                                         \
      float4 m;                                                             \
      m.x = vl.x + xri.x + ev.x; m.y = vl.y + xri.y + ev.y;                 \
      m.z = vl.z + xri.z + ev.z; m.w = vl.w + xri.w + ev.w;                 \
      m.x = m.x >= 0.f ? m.x : NEG * m.x;                                   \
      m.y = m.y >= 0.f ? m.y : NEG * m.y;                                   \
      m.z = m.z >= 0.f ? m.z : NEG * m.z;                                   \
      m.w = m.w >= 0.f ? m.w : NEG * m.w;                                   \
      float s = m.x * a4.x + m.y * a4.y + m.z * a4.z + m.w * a4.w;          \
      s += __shfl_xor(s, 1); s += __shfl_xor(s, 2);                         \
      s += __shfl_xor(s, 4); s += __shfl_xor(s, 8);                         \
      float ex = __expf(s);                                                 \
      acc.x += ex * vl.x; acc.y += ex * vl.y;                               \
      acc.z += ex * vl.z; acc.w += ex * vl.w;                               \
      evs.x += ev.x; evs.y += ev.y; evs.z += ev.z; evs.w += ev.w;           \
      den += ex;                                                            \
    }
    CS(0) CS(1) CS(2) CS(3) CS(4) CS(5) CS(6) CS(7)
#undef CS
  }

  // self-loop: mean(attr)@We == mean(evec) (linearity) — all in registers
  float invd = 1.0f / fmaxf((float)d, 1.0f);
  float4 m;
  m.x = xli.x + xri.x + evs.x * invd;
  m.y = xli.y + xri.y + evs.y * invd;
  m.z = xli.z + xri.z + evs.z * invd;
  m.w = xli.w + xri.w + evs.w * invd;
  m.x = m.x >= 0.f ? m.x : NEG * m.x;
  m.y = m.y >= 0.f ? m.y : NEG * m.y;
  m.z = m.z >= 0.f ? m.z : NEG * m.z;
  m.w = m.w >= 0.f ? m.w : NEG * m.w;
  float s = m.x * a4.x + m.y * a4.y + m.z * a4.z + m.w * a4.w;
  s += __shfl_xor(s, 1); s += __shfl_xor(s, 2);
  s += __shfl_xor(s, 4); s += __shfl_xor(s, 8);
  float exs = __expf(s);
  float inv = 1.0f / (den + exs);
  float4 o;
  o.x = (acc.x + exs * xli.x) * inv;
  o.y = (acc.y + exs * xli.y) * inv;
  o.z = (acc.z + exs * xli.z) * inv;
  o.w = (acc.w + exs * xli.w) * inv;
  *(float4*)(out + (size_t)i * DO + k0) = o;
}

// ======== fallback path (R4, used when ws_size < P_NEED) ========
__global__ __launch_bounds__(256) void k_place(const int* __restrict__ ei,
                                               const float* __restrict__ attr,
                                               unsigned* __restrict__ cursor,
                                               unsigned* __restrict__ srcs,
                                               unsigned short* __restrict__ aperm) {
  int e = blockIdx.x * 256 + threadIdx.x;
  if (e >= EE) return;
  unsigned src = (unsigned)ei[e];
  unsigned dst = (unsigned)ei[EE + e];
  const float* ar = attr + (size_t)e * DE;
  unsigned short h[12];
#pragma unroll
  for (int j = 0; j < DE; ++j) h[j] = (unsigned short)f2bfs(ar[j]);
  h[11] = 0;
  unsigned pos = atomicAdd(&cursor[dst], 1u);
  srcs[pos] = src;
  uint2* rp = (uint2*)(aperm + (size_t)pos * 12);
  uint2 w0, w1, w2;
  w0.x = (unsigned)h[0] | ((unsigned)h[1] << 16);
  w0.y = (unsigned)h[2] | ((unsigned)h[3] << 16);
  w1.x = (unsigned)h[4] | ((unsigned)h[5] << 16);
  w1.y = (unsigned)h[6] | ((unsigned)h[7] << 16);
  w2.x = (unsigned)h[8] | ((unsigned)h[9] << 16);
  w2.y = (unsigned)h[10];
  rp[0] = w0; rp[1] = w1; rp[2] = w2;
}

__device__ inline void consume_edge(uint2 raw, float atv,
                                    const float4* __restrict__ Wreg,
                                    float4 a4, float4 xri, float4& acc,
                                    float& denom, float& asum) {
  float4 vl = bf4_to_f4(raw);
  float4 ev = {0.f, 0.f, 0.f, 0.f};
#pragma unroll
  for (int j = 0; j < DE; ++j) {
    float a = __shfl(atv, j, 16);
    ev.x += a * Wreg[j].x; ev.y += a * Wreg[j].y;
    ev.z += a * Wreg[j].z; ev.w += a * Wreg[j].w;
  }
  float4 m;
  m.x = vl.x + xri.x + ev.x;
  m.y = vl.y + xri.y + ev.y;
  m.z = vl.z + xri.z + ev.z;
  m.w = vl.w + xri.w + ev.w;
  m.x = m.x >= 0.f ? m.x : NEG * m.x;
  m.y = m.y >= 0.f ? m.y : NEG * m.y;
  m.z = m.z >= 0.f ? m.z : NEG * m.z;
  m.w = m.w >= 0.f ? m.w : NEG * m.w;
  float s = m.x * a4.x + m.y * a4.y + m.z * a4.z + m.w * a4.w;
  s += __shfl_xor(s, 1);
  s += __shfl_xor(s, 2);
  s += __shfl_xor(s, 4);
  s += __shfl_xor(s, 8);
  float ex = __expf(s);
  acc.x += ex * vl.x; acc.y += ex * vl.y;
  acc.z += ex * vl.z; acc.w += ex * vl.w;
  denom += ex;
  asum += atv;
}

__global__ __launch_bounds__(256) void kf_aperm(
    const unsigned short* __restrict__ xlb, const unsigned short* __restrict__ xrb,
    const unsigned short* __restrict__ aperm, const float* __restrict__ We,
    const float* __restrict__ att, const unsigned* __restrict__ start,
    const unsigned* __restrict__ deg, const unsigned* __restrict__ srcs,
    float* __restrict__ out) {
  int t = blockIdx.x * 256 + threadIdx.x;
  int i = t >> 4;
  int g = t & 15;
  if (i >= NN) return;
  unsigned s0 = start[i];
  unsigned d = deg[i];
  int k0 = g * 4;
  float4 Wreg[DE];
#pragma unroll
  for (int j = 0; j < DE; ++j) Wreg[j] = *(const float4*)(We + j * DO + k0);
  const float4 a4 = *(const float4*)(att + k0);
  float4 xri = bf4_to_f4(*(const uint2*)(xrb + (size_t)i * DO + k0));
  float4 acc = {0.f, 0.f, 0.f, 0.f};
  float denom = 0.f;
  float asum = 0.f;
  for (unsigned c = 0; c < d; c += 16) {
    unsigned rem = d - c;
    if (rem > 16) rem = 16;
    unsigned sv = srcs[s0 + c + ((unsigned)g < rem ? (unsigned)g : rem - 1)];
#define LD(ii)                                                            \
    uint2 R##ii = {0u, 0u};                                               \
    if ((unsigned)ii < rem) {                                             \
      unsigned s_ = __shfl(sv, ii, 16);                                   \
      R##ii = *(const uint2*)(xlb + (size_t)s_ * DO + k0);                \
    }
    LD(0) LD(1) LD(2) LD(3) LD(4) LD(5) LD(6) LD(7)
    LD(8) LD(9) LD(10) LD(11) LD(12) LD(13) LD(14) LD(15)
#undef LD
#define LA(ii)                                                            \
    float A##ii = 0.f;                                                    \
    if ((unsigned)ii < rem && g < DE)                                     \
      A##ii = bfu_to_f(aperm[(size_t)(s0 + c + ii) * 12 + g]);
    LA(0) LA(1) LA(2) LA(3) LA(4) LA(5) LA(6) LA(7)
    LA(8) LA(9) LA(10) LA(11) LA(12) LA(13) LA(14) LA(15)
#undef LA
#define CS(ii)                                                            \
    if ((unsigned)ii < rem)                                               \
      consume_edge(R##ii, A##ii, Wreg, a4, xri, acc, denom, asum);
    CS(0) CS(1) CS(2) CS(3) CS(4) CS(5) CS(6) CS(7)
    CS(8) CS(9) CS(10) CS(11) CS(12) CS(13) CS(14) CS(15)
#undef CS
  }
  float la = asum / fmaxf((float)d, 1.0f);
  float4 ev = {0.f, 0.f, 0.f, 0.f};
#pragma unroll
  for (int j = 0; j < DE; ++j) {
    float aj = __shfl(la, j, 16);
    ev.x += aj * Wreg[j].x; ev.y += aj * Wreg[j].y;
    ev.z += aj * Wreg[j].z; ev.w += aj * Wreg[j].w;
  }
  float4 xli = bf4_to_f4(*(const uint2*)(xlb + (size_t)i * DO + k0));
  float4 m;
  m.x = xli.x + xri.x + ev.x;
  m.y = xli.y + xri.y + ev.y;
  m.z = xli.z + xri.z + ev.z;
  m.w = xli.w + xri.w + ev.w;
  m.x = m.x >= 0.f ? m.x : NEG * m.x;
  m.y = m.y >= 0.f ? m.y : NEG * m.y;
  m.z = m.z >= 0.f ? m.z : NEG * m.z;
  m.w = m.w >= 0.f ? m.w : NEG * m.w;
  float s = m.x * a4.x + m.y * a4.y + m.z * a4.z + m.w * a4.w;
  s += __shfl_xor(s, 1);
  s += __shfl_xor(s, 2);
  s += __shfl_xor(s, 4);
  s += __shfl_xor(s, 8);
  float exs = __expf(s);
  float inv = 1.0f / (denom + exs);
  float4 o;
  o.x = (acc.x + exs * xli.x) * inv;
  o.y = (acc.y + exs * xli.y) * inv;
  o.z = (acc.z + exs * xli.z) * inv;
  o.w = (acc.w + exs * xli.w) * inv;
  *(float4*)(out + (size_t)i * DO + k0) = o;
}

extern "C" void kernel_launch(void* const* d_in, const int* in_sizes, int n_in,
                              void* d_out, int out_size, void* d_ws, size_t ws_size,
                              hipStream_t stream) {
  const float* x    = (const float*)d_in[0];
  const int*   ei   = (const int*)d_in[1];
  const float* attr = (const float*)d_in[2];
  const float* Wl   = (const float*)d_in[3];
  const float* Wr   = (const float*)d_in[4];
  const float* We   = (const float*)d_in[5];
  const float* att  = (const float*)d_in[6];
  float* out = (float*)d_out;

  char* ws = (char*)d_ws;
  unsigned short* xrb  = (unsigned short*)(ws + XRB_B);
  unsigned short* xlb  = (unsigned short*)(ws + XLB_B);
  unsigned*       srcs = (unsigned*)(ws + SRC_B);

  bool primary = ws_size >= P_NEED;  // constant across calls -> graph-safe

  unsigned* start   = (unsigned*)(ws + (primary ? P_START : F_START));
  unsigned* cursor  = (unsigned*)(ws + (primary ? P_CUR : F_CUR));
  unsigned* deg     = (unsigned*)(ws + (primary ? P_DEG : F_DEG));
  unsigned* counter = (unsigned*)(ws + (primary ? P_CNT : F_CNT));

  hipMemsetAsync(deg, 0, (size_t)(NN + 1) * sizeof(unsigned), stream);

  k_gemm_deg<<<NGB + (EE + 255) / 256, 256, 0, stream>>>(x, Wl, Wr, ei,
                                                         xlb, xrb, deg);
  k_scan<<<(NN + 255) / 256, 256, 0, stream>>>(deg, start, cursor, counter);
  if (primary) {
    unsigned short* evec = (unsigned short*)(ws + EV_B);
    k_evec<<<4096, 256, 0, stream>>>(ei, attr, We, cursor, srcs, evec);
    k_fused<<<(NN * 16) / 128, 128, 0, stream>>>(xlb, xrb, evec, att,
                                                 start, deg, srcs, out);
  } else {
    unsigned short* aperm = (unsigned short*)(ws + APERM_B);
    k_place<<<(EE + 255) / 256, 256, 0, stream>>>(ei, attr, cursor, srcs, aperm);
    kf_aperm<<<(NN * 16) / 256, 256, 0, stream>>>(xlb, xrb, aperm, We, att,
                                                  start, deg, srcs, out);
  }
}